// Round 1
// baseline (1167.782 us; speedup 1.0000x reference)
//
#include <hip/hip_runtime.h>
#include <hip/hip_bf16.h>

#define Dc   192
#define D2c  384
#define Hc   48
#define Wc   48
#define BSc  2
#define NYc  2304   // 48*48

#define BM 64
#define BN 64
#define BK 16

enum { EPI_BIAS = 0, EPI_BNRELU = 1, EPI_BNSIGMUL = 2 };

// ---------------------------------------------------------------------------
// positional-encoding add: out[b,c,n] = in[b,c,n] + pe2d(C)[c,n]
// ---------------------------------------------------------------------------
__global__ __launch_bounds__(256)
void add_pe_kernel(const float* __restrict__ in, float* __restrict__ out,
                   int C, int total) {
    int idx = blockIdx.x * 256 + threadIdx.x;
    if (idx >= total) return;
    int n = idx % NYc;
    int c = (idx / NYc) % C;
    int x = n % Wc, y = n / Wc;
    int dh = C >> 1;
    float pos;
    int i;
    if (c < dh) { i = c >> 1;        pos = (float)x; }
    else        { i = (c - dh) >> 1; pos = (float)y; }
    // div[i] = exp(2i * (-ln(10000)/dh))
    float divv = expf((float)(2 * i) * (-9.210340371976184f / (float)dh));
    float ang = pos * divv;
    float pe = (c & 1) ? cosf(ang) : sinf(ang);
    out[idx] = in[idx] + pe;
}

// ---------------------------------------------------------------------------
// up_w (O,C,3,3) -> up_wt (O, tap*C + c)  so im2col GEMM A-loads coalesce
// ---------------------------------------------------------------------------
__global__ __launch_bounds__(256)
void transpose_up_kernel(const float* __restrict__ w, float* __restrict__ wt) {
    const int TOT = D2c * D2c * 9;
    int idx = blockIdx.x * 256 + threadIdx.x;
    if (idx >= TOT) return;
    int tap = idx % 9;
    int c   = (idx / 9) % D2c;
    int o   = idx / (9 * D2c);
    wt[o * (9 * D2c) + tap * D2c + c] = w[idx];
}

// ---------------------------------------------------------------------------
// fp32 tiled GEMM: out[b, o+chanOff, n] = EPI( sum_k A[o,k] * B(b,k,n) + bias[o] )
//   non-IM2COL: B(b,k,n) = X[b*xStride + k*NYc + n]
//   IM2COL:     k = tap*C + c ;  B = X[b*xStride + c*NYc + shifted(n, tap)] (0 pad)
// M,N multiples of 64; K multiple of 16 -> no guards.
// ---------------------------------------------------------------------------
template<int EPI, bool IM2COL>
__global__ __launch_bounds__(256)
void gemm_kernel(const float* __restrict__ A, const float* __restrict__ X,
                 const float* __restrict__ bias,
                 const float* __restrict__ bng, const float* __restrict__ bnb,
                 const float* __restrict__ smul,
                 float* __restrict__ out,
                 int M, int K, int C,
                 long xStride, long outStride, int chanOff, long smulStride)
{
    int b = blockIdx.z;
    const float* Xb = X + (long)b * xStride;
    float* outb = out + (long)b * outStride;
    int n0 = blockIdx.x * BN;
    int m0 = blockIdx.y * BM;

    __shared__ __align__(16) float As[BK][BM + 4];   // +4 pad: 2-way banks only
    __shared__ __align__(16) float Bs[BK][BN];

    int t  = threadIdx.x;
    int tx = t & 15, ty = t >> 4;

    float acc[4][4] = {};

    int ka    = t & (BK - 1);   // 0..15 (A k index, coalesced)
    int mBase = t >> 4;         // 0..15
    int nb    = t & 63;         // 0..63 (B n index, coalesced)
    int kb    = t >> 6;         // 0..3

    for (int k0 = 0; k0 < K; k0 += BK) {
        #pragma unroll
        for (int i = 0; i < 4; ++i) {
            int m = mBase + 16 * i;
            As[ka][m] = A[(long)(m0 + m) * K + (k0 + ka)];
        }
        #pragma unroll
        for (int i = 0; i < 4; ++i) {
            int k  = kb + 4 * i;
            int gk = k0 + k;
            float v;
            if (!IM2COL) {
                v = Xb[(long)gk * NYc + (n0 + nb)];
            } else {
                int tap = gk / C;
                int cc  = gk - tap * C;
                int p   = n0 + nb;
                int py  = p / Wc + tap / 3 - 1;
                int px  = p % Wc + tap % 3 - 1;
                v = (py >= 0 && py < Hc && px >= 0 && px < Wc)
                        ? Xb[(long)cc * NYc + py * Wc + px] : 0.0f;
            }
            Bs[k][nb] = v;
        }
        __syncthreads();
        #pragma unroll
        for (int k = 0; k < BK; ++k) {
            float4 av = *(const float4*)&As[k][ty * 4];
            float4 bv = *(const float4*)&Bs[k][tx * 4];
            float a[4] = {av.x, av.y, av.z, av.w};
            float bb[4] = {bv.x, bv.y, bv.z, bv.w};
            #pragma unroll
            for (int i = 0; i < 4; ++i)
                #pragma unroll
                for (int j = 0; j < 4; ++j)
                    acc[i][j] = fmaf(a[i], bb[j], acc[i][j]);
        }
        __syncthreads();
    }

    #pragma unroll
    for (int i = 0; i < 4; ++i) {
        int o = m0 + ty * 4 + i;
        float bi = bias[o];
        float g = 1.0f, bn2 = 0.0f;
        if (EPI != EPI_BIAS) { g = bng[o]; bn2 = bnb[o]; }
        float r[4];
        #pragma unroll
        for (int j = 0; j < 4; ++j) {
            float v = acc[i][j] + bi;
            if (EPI == EPI_BNRELU) {
                v = fmaxf(fmaf(v, g, bn2), 0.0f);
            } else if (EPI == EPI_BNSIGMUL) {
                v = fmaf(v, g, bn2);
                v = 1.0f / (1.0f + __expf(-v));
            }
            r[j] = v;
        }
        long col = (long)n0 + tx * 4;
        if (EPI == EPI_BNSIGMUL) {
            float4 sv = *(const float4*)&smul[(long)b * smulStride + (long)o * NYc + col];
            r[0] *= sv.x; r[1] *= sv.y; r[2] *= sv.z; r[3] *= sv.w;
        }
        *(float4*)&outb[(long)(o + chanOff) * NYc + col] = *(float4*)r;
    }
}

// ---------------------------------------------------------------------------
// fused flash-style attention, fp32.
// grid (36 qblocks, 16 b*h), 256 threads.  4 lanes per query, 16 keys each.
// Qt/Kt: (b, 384, 2304) channel-major; Vt/Zt: (b, 192, 2304).
// scale = 1/sqrt(192) (reference divides by sqrt(D)).
// ---------------------------------------------------------------------------
__global__ __launch_bounds__(256)
void attn_kernel(const float* __restrict__ Qt, const float* __restrict__ Kt,
                 const float* __restrict__ Vt, float* __restrict__ Zt)
{
    int qb = blockIdx.x;          // 0..35
    int bh = blockIdx.y;          // 0..15
    int b = bh >> 3, h = bh & 7;
    const float* Q  = Qt + ((long)b * D2c + h * 48) * NYc;
    const float* Kp = Kt + ((long)b * D2c + h * 48) * NYc;
    const float* Vp = Vt + ((long)b * Dc  + h * 24) * NYc;
    float*       Z  = Zt + ((long)b * Dc  + h * 24) * NYc;
    int q0 = qb * 64;

    __shared__ __align__(16) float Qs[48][64];
    __shared__ __align__(16) float Ks[48][64];
    __shared__ __align__(16) float Vs[24][64];

    int t = threadIdx.x;
    {
        int qq = t & 63, d0 = t >> 6;
        for (int d = d0; d < 48; d += 4) Qs[d][qq] = Q[(long)d * NYc + q0 + qq];
    }

    int q = t >> 2;   // 0..63
    int g = t & 3;    // 0..3   (lanes q*4+g: xor 1/2 stay in group)

    float m_run = -1e30f, l_run = 0.0f;
    float acc[24];
    #pragma unroll
    for (int i = 0; i < 24; ++i) acc[i] = 0.0f;
    const float scale = 0.072168784f;   // 1/sqrt(192)

    for (int kt = 0; kt < 36; ++kt) {
        int k0 = kt * 64;
        {
            int kk = t & 63, d0 = t >> 6;
            for (int d = d0; d < 48; d += 4) Ks[d][kk] = Kp[(long)d * NYc + k0 + kk];
            for (int d = d0; d < 24; d += 4) Vs[d][kk] = Vp[(long)d * NYc + k0 + kk];
        }
        __syncthreads();

        float s[16];
        #pragma unroll
        for (int j = 0; j < 16; ++j) s[j] = 0.0f;
        #pragma unroll 4
        for (int d = 0; d < 48; ++d) {
            float qv = Qs[d][q];
            const float4* kr = (const float4*)&Ks[d][g * 16];
            #pragma unroll
            for (int j4 = 0; j4 < 4; ++j4) {
                float4 kv = kr[j4];
                s[j4 * 4 + 0] = fmaf(qv, kv.x, s[j4 * 4 + 0]);
                s[j4 * 4 + 1] = fmaf(qv, kv.y, s[j4 * 4 + 1]);
                s[j4 * 4 + 2] = fmaf(qv, kv.z, s[j4 * 4 + 2]);
                s[j4 * 4 + 3] = fmaf(qv, kv.w, s[j4 * 4 + 3]);
            }
        }
        float mt = -1e30f;
        #pragma unroll
        for (int j = 0; j < 16; ++j) { s[j] *= scale; mt = fmaxf(mt, s[j]); }
        mt = fmaxf(mt, __shfl_xor(mt, 1));
        mt = fmaxf(mt, __shfl_xor(mt, 2));
        float m_new = fmaxf(m_run, mt);
        float alpha = __expf(m_run - m_new);
        float p[16];
        float psum = 0.0f;
        #pragma unroll
        for (int j = 0; j < 16; ++j) { p[j] = __expf(s[j] - m_new); psum += p[j]; }
        l_run = fmaf(l_run, alpha, psum);
        m_run = m_new;

        #pragma unroll
        for (int dv = 0; dv < 24; ++dv) {
            const float4* vr = (const float4*)&Vs[dv][g * 16];
            float a = acc[dv] * alpha;
            #pragma unroll
            for (int j4 = 0; j4 < 4; ++j4) {
                float4 vv = vr[j4];
                a = fmaf(p[j4 * 4 + 0], vv.x, a);
                a = fmaf(p[j4 * 4 + 1], vv.y, a);
                a = fmaf(p[j4 * 4 + 2], vv.z, a);
                a = fmaf(p[j4 * 4 + 3], vv.w, a);
            }
            acc[dv] = a;
        }
        __syncthreads();
    }

    #pragma unroll
    for (int dv = 0; dv < 24; ++dv) {
        float v = acc[dv];
        v += __shfl_xor(v, 1);
        v += __shfl_xor(v, 2);
        acc[dv] = v;
    }
    float l = l_run;
    l += __shfl_xor(l, 1);
    l += __shfl_xor(l, 2);
    float inv = 1.0f / l;
    #pragma unroll
    for (int jj = 0; jj < 6; ++jj) {
        int dv = g * 6 + jj;
        Z[(long)dv * NYc + q0 + q] = acc[dv] * inv;
    }
}

// ---------------------------------------------------------------------------
extern "C" void kernel_launch(void* const* d_in, const int* in_sizes, int n_in,
                              void* d_out, int out_size, void* d_ws, size_t ws_size,
                              hipStream_t stream) {
    const float* y       = (const float*)d_in[0];
    const float* s       = (const float*)d_in[1];
    const float* wq_w    = (const float*)d_in[2];
    const float* wq_b    = (const float*)d_in[3];
    const float* wk_w    = (const float*)d_in[4];
    const float* wk_b    = (const float*)d_in[5];
    const float* wv_w    = (const float*)d_in[6];
    const float* wv_b    = (const float*)d_in[7];
    const float* conv1_w = (const float*)d_in[8];
    const float* conv1_b = (const float*)d_in[9];
    const float* bn1_g   = (const float*)d_in[10];
    const float* bn1_b   = (const float*)d_in[11];
    const float* conv2_w = (const float*)d_in[12];
    const float* conv2_b = (const float*)d_in[13];
    const float* bn2_g   = (const float*)d_in[14];
    const float* bn2_b   = (const float*)d_in[15];
    const float* up_w    = (const float*)d_in[16];
    const float* up_b    = (const float*)d_in[17];
    const float* conv3_w = (const float*)d_in[18];
    const float* conv3_b = (const float*)d_in[19];
    const float* bn3_g   = (const float*)d_in[20];
    const float* bn3_b   = (const float*)d_in[21];
    const float* sig_w   = (const float*)d_in[22];
    const float* sig_b   = (const float*)d_in[23];
    const float* bnsig_g = (const float*)d_in[24];
    const float* bnsig_b = (const float*)d_in[25];
    float* out = (float*)d_out;

    const long SZ_Y2 = (long)D2c * NYc;        // 884736 per batch (384 ch)
    const long SZ_Y1 = (long)Dc  * NYc;        // 442368 per batch (192 ch)

    float* ws    = (float*)d_ws;
    float* y_pe  = ws;                          // 2*SZ_Y2 = 1769472
    float* s_pe  = y_pe + 2 * SZ_Y2;            // 2*SZ_Y1 =  884736
    float* y_c1  = s_pe + 2 * SZ_Y1;            // 1769472
    float* y_up  = y_c1 + 2 * SZ_Y2;            // 1769472
    float* s_c2  = y_up + 2 * SZ_Y2;            //  884736
    float* Vt    = s_c2 + 2 * SZ_Y1;            //  884736
    float* up_wt = Vt   + 2 * SZ_Y1;            // 1327104
    // aliases (producer of the original buffer is dead by the time these write)
    float* Qt = y_pe;   // after conv1 + up conv
    float* Kt = y_up;   // after conv3
    float* Zt = y_c1;   // after Q,K projections

    const int total_y = BSc * D2c * NYc;
    const int total_s = BSc * Dc * NYc;

    add_pe_kernel<<<total_y / 256, 256, 0, stream>>>(y, y_pe, D2c, total_y);
    add_pe_kernel<<<total_s / 256, 256, 0, stream>>>(s, s_pe, Dc, total_s);
    transpose_up_kernel<<<(D2c * D2c * 9) / 256, 256, 0, stream>>>(up_w, up_wt);

    dim3 blk(256);
    // conv1: y_pe -> y_c1  (384x384), BN+ReLU
    gemm_kernel<EPI_BNRELU, false><<<dim3(36, 6, 2), blk, 0, stream>>>(
        conv1_w, y_pe, conv1_b, bn1_g, bn1_b, nullptr, y_c1,
        D2c, D2c, D2c, SZ_Y2, SZ_Y2, 0, 0);
    // conv2: s_pe -> s_c2  (192x192), BN+ReLU
    gemm_kernel<EPI_BNRELU, false><<<dim3(36, 3, 2), blk, 0, stream>>>(
        conv2_w, s_pe, conv2_b, bn2_g, bn2_b, nullptr, s_c2,
        Dc, Dc, Dc, SZ_Y1, SZ_Y1, 0, 0);
    // up: 3x3 conv y_pe -> y_up (384 out, K=3456 im2col), bias only
    gemm_kernel<EPI_BIAS, true><<<dim3(36, 6, 2), blk, 0, stream>>>(
        up_wt, y_pe, up_b, nullptr, nullptr, nullptr, y_up,
        D2c, 9 * D2c, D2c, SZ_Y2, SZ_Y2, 0, 0);
    // conv3: y_up -> d_out channels [192,384), BN+ReLU
    gemm_kernel<EPI_BNRELU, false><<<dim3(36, 3, 2), blk, 0, stream>>>(
        conv3_w, y_up, conv3_b, bn3_g, bn3_b, nullptr, out,
        Dc, D2c, D2c, SZ_Y2, SZ_Y2, Dc, 0);
    // Q projection: y_c1 -> Qt (384x384)
    gemm_kernel<EPI_BIAS, false><<<dim3(36, 6, 2), blk, 0, stream>>>(
        wq_w, y_c1, wq_b, nullptr, nullptr, nullptr, Qt,
        D2c, D2c, D2c, SZ_Y2, SZ_Y2, 0, 0);
    // K projection: y_c1 -> Kt (384x384)
    gemm_kernel<EPI_BIAS, false><<<dim3(36, 6, 2), blk, 0, stream>>>(
        wk_w, y_c1, wk_b, nullptr, nullptr, nullptr, Kt,
        D2c, D2c, D2c, SZ_Y2, SZ_Y2, 0, 0);
    // V projection: s_c2 -> Vt (192x192)
    gemm_kernel<EPI_BIAS, false><<<dim3(36, 3, 2), blk, 0, stream>>>(
        wv_w, s_c2, wv_b, nullptr, nullptr, nullptr, Vt,
        Dc, Dc, Dc, SZ_Y1, SZ_Y1, 0, 0);
    // attention: Qt,Kt,Vt -> Zt
    attn_kernel<<<dim3(36, 16), blk, 0, stream>>>(Qt, Kt, Vt, Zt);
    // sigmoid gate * s_pe -> d_out channels [0,192)
    gemm_kernel<EPI_BNSIGMUL, false><<<dim3(36, 3, 2), blk, 0, stream>>>(
        sig_w, Zt, sig_b, bnsig_g, bnsig_b, s_pe, out,
        Dc, Dc, Dc, SZ_Y1, SZ_Y2, 0, SZ_Y1);
}

// Round 2
// 222.620 us; speedup vs baseline: 5.2456x; 5.2456x over previous
//
#include <hip/hip_runtime.h>
#include <hip/hip_bf16.h>

#define Dc   192
#define D2c  384
#define NYc  2304   // 48*48

typedef __attribute__((ext_vector_type(8))) short short8;
typedef __attribute__((ext_vector_type(4))) float f32x4;

__device__ __forceinline__ unsigned short f2bf(float f) {
    unsigned int u = __float_as_uint(f);
    u += 0x7FFFu + ((u >> 16) & 1u);   // RNE
    return (unsigned short)(u >> 16);
}

// ---------------------------------------------------------------------------
// positional encoding value for channel c, token n, channel count C
// ---------------------------------------------------------------------------
__device__ __forceinline__ float pe_val(int c, int n, int C) {
    int x = n % 48, y = n / 48;
    int dh = C >> 1;
    float pos; int i;
    if (c < dh) { i = c >> 1;        pos = (float)x; }
    else        { i = (c - dh) >> 1; pos = (float)y; }
    float divv = expf((float)(2 * i) * (-9.210340371976184f / (float)dh));
    float ang = pos * divv;
    return (c & 1) ? cosf(ang) : sinf(ang);
}

// y (fp32 ch-major) -> y_pe_tok (bf16 token-major [b][n][384])
__global__ __launch_bounds__(256)
void pe_y_kernel(const float* __restrict__ y, unsigned short* __restrict__ ytok) {
    int idx = blockIdx.x * 256 + threadIdx.x;         // b*384*2304 + c*2304 + n
    int n = idx % NYc; int c = (idx / NYc) % D2c; int b = idx / (NYc * D2c);
    float v = y[idx] + pe_val(c, n, D2c);
    ytok[(long)b * NYc * D2c + (long)n * D2c + c] = f2bf(v);
}

// s -> s_pe_tok (bf16 token-major) AND s_pe_ch (fp32 ch-major, for final gate)
__global__ __launch_bounds__(256)
void pe_s_kernel(const float* __restrict__ s, unsigned short* __restrict__ stok,
                 float* __restrict__ sch) {
    int idx = blockIdx.x * 256 + threadIdx.x;         // b*192*2304 + c*2304 + n
    int n = idx % NYc; int c = (idx / NYc) % Dc; int b = idx / (NYc * Dc);
    float v = s[idx] + pe_val(c, n, Dc);
    sch[idx] = v;
    stok[(long)b * NYc * Dc + (long)n * Dc + c] = f2bf(v);
}

// fused fp32->bf16 conversion of the seven 1x1 weight matrices
__global__ __launch_bounds__(256)
void cvt_w_kernel(const float* __restrict__ w0, const float* __restrict__ w1,
                  const float* __restrict__ w2, const float* __restrict__ w3,
                  const float* __restrict__ w4, const float* __restrict__ w5,
                  const float* __restrict__ w6, unsigned short* __restrict__ dst) {
    int idx = blockIdx.x * 256 + threadIdx.x;   // total 626688
    const float* src; int off;
    if      (idx < 147456) { src = w0; off = idx; }
    else if (idx < 294912) { src = w1; off = idx - 147456; }
    else if (idx < 442368) { src = w2; off = idx - 294912; }
    else if (idx < 479232) { src = w3; off = idx - 442368; }
    else if (idx < 516096) { src = w4; off = idx - 479232; }
    else if (idx < 552960) { src = w5; off = idx - 516096; }
    else                   { src = w6; off = idx - 552960; }
    dst[idx] = f2bf(src[off]);
}

// up_w (O,C,3,3) fp32 -> up_wt bf16 [O][tap*384 + c]
__global__ __launch_bounds__(256)
void cvt_up_kernel(const float* __restrict__ w, unsigned short* __restrict__ wt) {
    int idx = blockIdx.x * 256 + threadIdx.x;   // total 384*3456
    int o = idx / 3456; int r = idx % 3456;
    int tap = r / 384;  int c = r % 384;
    wt[idx] = f2bf(w[((long)o * 384 + c) * 9 + tap]);
}

// ---------------------------------------------------------------------------
// Unified bf16 MFMA GEMM:  D[m][n] = sum_k A'[m][k] * B'[n][k]  (+ epilogue)
// A' and B' are row-major [free][k] bf16 (k contiguous). 64x64 tile, BK=32,
// 4 waves each 32x32 (2x2 of 16x16x32 mfma).
//  - orientation "T": A'=activations(tokens), B'=weights  -> out token-major
//  - orientation "C": A'=weights, B'=activations          -> out ch-major
// IM2COL: A' rows are im2col rows of a token-major [n][384] tensor (3x3 SAME).
// CH_M: channel (bias/bn) axis is m (true for orientation C) else n.
// ---------------------------------------------------------------------------
enum { E_BIAS = 0, E_BNRELU = 1, E_BNRELU_F32 = 2, E_SIG_F32 = 3 };

template<int EPI, bool IM2COL, bool CH_M>
__global__ __launch_bounds__(256)
void mfma_gemm(const unsigned short* __restrict__ Ar, long aBatch, int aPitch,
               const unsigned short* __restrict__ Br, long bBatch, int bPitch,
               int K,
               const float* __restrict__ bias, const float* __restrict__ bng,
               const float* __restrict__ bnb,
               const float* __restrict__ smul, long smulBatch,
               void* __restrict__ outv, long oBatch, int oPitch)
{
    int b = blockIdx.z;
    const unsigned short* A = Ar + (long)b * aBatch;
    const unsigned short* B = Br + (long)b * bBatch;
    int n0 = blockIdx.x * 64, m0 = blockIdx.y * 64;

    __shared__ __align__(16) unsigned short As[64][40];  // pitch 40: 80B rows
    __shared__ __align__(16) unsigned short Bs[64][40];

    int t = threadIdx.x;
    int lane = t & 63, w = t >> 6;
    int lr = lane & 15, lg = lane >> 4;
    int wm = (w >> 1) * 32, wn = (w & 1) * 32;
    int srow = t >> 2, sc4 = t & 3;

    f32x4 zero = {0.f, 0.f, 0.f, 0.f};
    f32x4 acc[2][2] = {{zero, zero}, {zero, zero}};

    for (int k0 = 0; k0 < K; k0 += 32) {
        uint4 av, bv;
        if (!IM2COL) {
            av = *(const uint4*)(A + (long)(m0 + srow) * aPitch + k0 + sc4 * 8);
        } else {
            int tap = k0 / 384;
            int rem = k0 - tap * 384 + sc4 * 8;
            int tok = m0 + srow;
            int py = tok / 48 + tap / 3 - 1;
            int px = tok % 48 + tap % 3 - 1;
            if (py >= 0 && py < 48 && px >= 0 && px < 48)
                av = *(const uint4*)(A + (long)(py * 48 + px) * aPitch + rem);
            else
                av = make_uint4(0, 0, 0, 0);
        }
        bv = *(const uint4*)(B + (long)(n0 + srow) * bPitch + k0 + sc4 * 8);
        *(uint4*)&As[srow][sc4 * 8] = av;
        *(uint4*)&Bs[srow][sc4 * 8] = bv;
        __syncthreads();

        short8 a0 = *(const short8*)&As[wm + lr][lg * 8];
        short8 a1 = *(const short8*)&As[wm + 16 + lr][lg * 8];
        short8 b0 = *(const short8*)&Bs[wn + lr][lg * 8];
        short8 b1 = *(const short8*)&Bs[wn + 16 + lr][lg * 8];
        acc[0][0] = __builtin_amdgcn_mfma_f32_16x16x32_bf16(a0, b0, acc[0][0], 0, 0, 0);
        acc[0][1] = __builtin_amdgcn_mfma_f32_16x16x32_bf16(a0, b1, acc[0][1], 0, 0, 0);
        acc[1][0] = __builtin_amdgcn_mfma_f32_16x16x32_bf16(a1, b0, acc[1][0], 0, 0, 0);
        acc[1][1] = __builtin_amdgcn_mfma_f32_16x16x32_bf16(a1, b1, acc[1][1], 0, 0, 0);
        __syncthreads();
    }

    float* outF = (float*)outv;
    unsigned short* outH = (unsigned short*)outv;
    long ob = (long)b * oBatch;
    #pragma unroll
    for (int i = 0; i < 2; ++i)
    #pragma unroll
    for (int j = 0; j < 2; ++j)
    #pragma unroll
    for (int r = 0; r < 4; ++r) {
        int gm = m0 + wm + i * 16 + lg * 4 + r;   // D row
        int gn = n0 + wn + j * 16 + lr;           // D col
        int ch = CH_M ? gm : gn;
        float v = acc[i][j][r] + bias[ch];
        if (EPI == E_BNRELU || EPI == E_BNRELU_F32)
            v = fmaxf(fmaf(v, bng[ch], bnb[ch]), 0.f);
        if (EPI == E_SIG_F32) {
            v = fmaf(v, bng[ch], bnb[ch]);
            v = 1.f / (1.f + __expf(-v));
            v *= smul[(long)b * smulBatch + (long)gm * NYc + gn];
        }
        long o = ob + (long)gm * oPitch + gn;
        if (EPI == E_BNRELU_F32 || EPI == E_SIG_F32) outF[o] = v;
        else                                         outH[o] = f2bf(v);
    }
}

// ---------------------------------------------------------------------------
// Fused MFMA flash attention.
// Q_tok/K_tok: bf16 [b][2304][384] (head slice h*48..h*48+47, zero-padded to
// 64 in LDS). V_ch: bf16 [b][192][2304]. Z_tok out: bf16 [b][2304][192].
// Block: 64 queries, 4 waves (16 q each). Key loop: 36 tiles of 64.
// scale = 1/sqrt(192) per reference.
// ---------------------------------------------------------------------------
__global__ __launch_bounds__(256)
void attn_kernel(const unsigned short* __restrict__ Qt,
                 const unsigned short* __restrict__ Kt,
                 const unsigned short* __restrict__ Vc,
                 unsigned short* __restrict__ Zt)
{
    int qb = blockIdx.x;                 // 0..35
    int bh = blockIdx.y;                 // 0..15
    int b = bh >> 3, h = bh & 7;
    const unsigned short* Q  = Qt + (long)b * NYc * D2c + h * 48;
    const unsigned short* Kp = Kt + (long)b * NYc * D2c + h * 48;
    const unsigned short* V  = Vc + (long)b * Dc * NYc + (long)(h * 24) * NYc;
    unsigned short*       Z  = Zt + (long)b * NYc * Dc + h * 24;

    __shared__ __align__(16) unsigned short Qs[64][72];
    __shared__ __align__(16) unsigned short Ks[64][72];
    __shared__ __align__(16) unsigned short Vs[32][72];
    __shared__ __align__(16) unsigned short Ps[4][16][72];

    int t = threadIdx.x, lane = t & 63, w = t >> 6;
    int lr = lane & 15, lg = lane >> 4;
    int q0 = qb * 64;

    {   // stage Q once: rows 64 tokens x cols 0..47 data, 48..63 zeros
        int row = t >> 2, c4 = t & 3;
        const unsigned short* qr = Q + (long)(q0 + row) * D2c;
        *(uint4*)&Qs[row][c4 * 8] = *(const uint4*)(qr + c4 * 8);
        uint4 z = make_uint4(0, 0, 0, 0);
        uint4 v = (c4 < 2) ? *(const uint4*)(qr + 32 + c4 * 8) : z;
        *(uint4*)&Qs[row][32 + c4 * 8] = v;
    }

    float m_run[4] = {-1e30f, -1e30f, -1e30f, -1e30f};
    float l_run[4] = {0.f, 0.f, 0.f, 0.f};
    f32x4 O0 = {0.f, 0.f, 0.f, 0.f}, O1 = {0.f, 0.f, 0.f, 0.f};
    const float scale = 0.07216878364870323f;   // 1/sqrt(192)

    for (int kt = 0; kt < 36; ++kt) {
        int k0 = kt * 64;
        __syncthreads();
        {   // stage K tile (like Q) and V tile [32 dv][64 keys] (rows 24..31 zero)
            int row = t >> 2, c4 = t & 3;
            const unsigned short* kr = Kp + (long)(k0 + row) * D2c;
            *(uint4*)&Ks[row][c4 * 8] = *(const uint4*)(kr + c4 * 8);
            uint4 z = make_uint4(0, 0, 0, 0);
            uint4 v = (c4 < 2) ? *(const uint4*)(kr + 32 + c4 * 8) : z;
            *(uint4*)&Ks[row][32 + c4 * 8] = v;
            int vrow = t >> 3, vch = t & 7;
            uint4 vv = z;
            if (vrow < 24) vv = *(const uint4*)(V + (long)vrow * NYc + k0 + vch * 8);
            *(uint4*)&Vs[vrow][vch * 8] = vv;
        }
        __syncthreads();

        // S = Q K^T for this wave's 16 q rows x 64 keys
        short8 aq0 = *(const short8*)&Qs[w * 16 + lr][lg * 8];
        short8 aq1 = *(const short8*)&Qs[w * 16 + lr][32 + lg * 8];
        f32x4 sS[4];
        #pragma unroll
        for (int ks = 0; ks < 4; ++ks) {
            short8 bk0 = *(const short8*)&Ks[ks * 16 + lr][lg * 8];
            short8 bk1 = *(const short8*)&Ks[ks * 16 + lr][32 + lg * 8];
            f32x4 c = {0.f, 0.f, 0.f, 0.f};
            c = __builtin_amdgcn_mfma_f32_16x16x32_bf16(aq0, bk0, c, 0, 0, 0);
            c = __builtin_amdgcn_mfma_f32_16x16x32_bf16(aq1, bk1, c, 0, 0, 0);
            sS[ks] = c;
        }

        // online softmax per q row (row = lg*4 + r, cols = lane&15 + 16*ks)
        #pragma unroll
        for (int r = 0; r < 4; ++r) {
            float s0 = sS[0][r] * scale, s1 = sS[1][r] * scale;
            float s2 = sS[2][r] * scale, s3 = sS[3][r] * scale;
            float rm = fmaxf(fmaxf(s0, s1), fmaxf(s2, s3));
            rm = fmaxf(rm, __shfl_xor(rm, 1));
            rm = fmaxf(rm, __shfl_xor(rm, 2));
            rm = fmaxf(rm, __shfl_xor(rm, 4));
            rm = fmaxf(rm, __shfl_xor(rm, 8));
            float mn = fmaxf(m_run[r], rm);
            float al = __expf(m_run[r] - mn);
            m_run[r] = mn;
            float p0 = __expf(s0 - mn), p1 = __expf(s1 - mn);
            float p2 = __expf(s2 - mn), p3 = __expf(s3 - mn);
            l_run[r] = l_run[r] * al + (p0 + p1 + p2 + p3);   // lane-partial
            O0[r] *= al; O1[r] *= al;
            int qrow = lg * 4 + r;
            Ps[w][qrow][ 0 + lr] = f2bf(p0);
            Ps[w][qrow][16 + lr] = f2bf(p1);
            Ps[w][qrow][32 + lr] = f2bf(p2);
            Ps[w][qrow][48 + lr] = f2bf(p3);
        }

        // O += P V   (A=P [16q][64keys], B'=V_ch rows [dv][keys])
        short8 ap0 = *(const short8*)&Ps[w][lr][lg * 8];
        short8 ap1 = *(const short8*)&Ps[w][lr][32 + lg * 8];
        short8 bv00 = *(const short8*)&Vs[lr][lg * 8];
        short8 bv01 = *(const short8*)&Vs[lr][32 + lg * 8];
        short8 bv10 = *(const short8*)&Vs[16 + lr][lg * 8];
        short8 bv11 = *(const short8*)&Vs[16 + lr][32 + lg * 8];
        O0 = __builtin_amdgcn_mfma_f32_16x16x32_bf16(ap0, bv00, O0, 0, 0, 0);
        O0 = __builtin_amdgcn_mfma_f32_16x16x32_bf16(ap1, bv01, O0, 0, 0, 0);
        O1 = __builtin_amdgcn_mfma_f32_16x16x32_bf16(ap0, bv10, O1, 0, 0, 0);
        O1 = __builtin_amdgcn_mfma_f32_16x16x32_bf16(ap1, bv11, O1, 0, 0, 0);
    }

    #pragma unroll
    for (int r = 0; r < 4; ++r) {
        float l = l_run[r];
        l += __shfl_xor(l, 1);
        l += __shfl_xor(l, 2);
        l += __shfl_xor(l, 4);
        l += __shfl_xor(l, 8);
        float inv = 1.0f / l;
        int n = q0 + w * 16 + lg * 4 + r;
        unsigned short* zr = Z + (long)n * Dc;
        zr[lr] = f2bf(O0[r] * inv);                     // dv 0..15
        if (lr < 8) zr[16 + lr] = f2bf(O1[r] * inv);    // dv 16..23
    }
}

// ---------------------------------------------------------------------------
extern "C" void kernel_launch(void* const* d_in, const int* in_sizes, int n_in,
                              void* d_out, int out_size, void* d_ws, size_t ws_size,
                              hipStream_t stream) {
    const float* y       = (const float*)d_in[0];
    const float* s       = (const float*)d_in[1];
    const float* wq_w    = (const float*)d_in[2];
    const float* wq_b    = (const float*)d_in[3];
    const float* wk_w    = (const float*)d_in[4];
    const float* wk_b    = (const float*)d_in[5];
    const float* wv_w    = (const float*)d_in[6];
    const float* wv_b    = (const float*)d_in[7];
    const float* conv1_w = (const float*)d_in[8];
    const float* conv1_b = (const float*)d_in[9];
    const float* bn1_g   = (const float*)d_in[10];
    const float* bn1_b   = (const float*)d_in[11];
    const float* conv2_w = (const float*)d_in[12];
    const float* conv2_b = (const float*)d_in[13];
    const float* bn2_g   = (const float*)d_in[14];
    const float* bn2_b   = (const float*)d_in[15];
    const float* up_w    = (const float*)d_in[16];
    const float* up_b    = (const float*)d_in[17];
    const float* conv3_w = (const float*)d_in[18];
    const float* conv3_b = (const float*)d_in[19];
    const float* bn3_g   = (const float*)d_in[20];
    const float* bn3_b   = (const float*)d_in[21];
    const float* sig_w   = (const float*)d_in[22];
    const float* sig_b   = (const float*)d_in[23];
    const float* bnsig_g = (const float*)d_in[24];
    const float* bnsig_b = (const float*)d_in[25];

    unsigned short* wsp = (unsigned short*)d_ws;
    unsigned short* wcvt = wsp;                      // 626688
    unsigned short* upwt = wcvt + 626688;            // 1327104
    unsigned short* y_pe = upwt + 1327104;           // 1769472
    unsigned short* s_pe = y_pe + 1769472;           //  884736
    unsigned short* y_c1 = s_pe + 884736;            // 1769472
    unsigned short* s_c2 = y_c1 + 1769472;           //  884736
    unsigned short* y_up = s_c2 + 884736;            // 1769472
    unsigned short* Qtok = y_up + 1769472;           // 1769472
    unsigned short* Ktok = Qtok + 1769472;           // 1769472
    unsigned short* Vch  = Ktok + 1769472;           //  884736
    unsigned short* Ztok = Vch + 884736;             //  884736
    float*          s_ch = (float*)(Ztok + 884736);  //  884736 fp32

    const unsigned short* conv1wb = wcvt;
    const unsigned short* wqb     = wcvt + 147456;
    const unsigned short* wkb     = wcvt + 294912;
    const unsigned short* conv2wb = wcvt + 442368;
    const unsigned short* wvb     = wcvt + 479232;
    const unsigned short* sigwb   = wcvt + 516096;
    const unsigned short* conv3wb = wcvt + 552960;

    const long SY2 = (long)D2c * NYc;   // 884736
    const long SY1 = (long)Dc * NYc;    // 442368

    pe_y_kernel<<<(2 * D2c * NYc) / 256, 256, 0, stream>>>(y, y_pe);
    pe_s_kernel<<<(2 * Dc * NYc) / 256, 256, 0, stream>>>(s, s_pe, s_ch);
    cvt_w_kernel<<<626688 / 256, 256, 0, stream>>>(conv1_w, wq_w, wk_w, conv2_w,
                                                   wv_w, sig_w, conv3_w, wcvt);
    cvt_up_kernel<<<1327104 / 256, 256, 0, stream>>>(up_w, upwt);

    dim3 blk(256);
    // conv1 (T): y_pe_tok x conv1_w -> y_c1_tok, BN+ReLU
    mfma_gemm<E_BNRELU, false, false><<<dim3(6, 36, 2), blk, 0, stream>>>(
        y_pe, SY2, D2c, conv1wb, 0, D2c, D2c,
        conv1_b, bn1_g, bn1_b, nullptr, 0, y_c1, SY2, D2c);
    // conv2 (T): s_pe_tok x conv2_w -> s_c2_tok, BN+ReLU
    mfma_gemm<E_BNRELU, false, false><<<dim3(3, 36, 2), blk, 0, stream>>>(
        s_pe, SY1, Dc, conv2wb, 0, Dc, Dc,
        conv2_b, bn2_g, bn2_b, nullptr, 0, s_c2, SY1, Dc);
    // up (T, im2col): y_pe_tok x up_wt -> y_up_tok, bias
    mfma_gemm<E_BIAS, true, false><<<dim3(6, 36, 2), blk, 0, stream>>>(
        y_pe, SY2, D2c, upwt, 0, 9 * D2c, 9 * D2c,
        up_b, nullptr, nullptr, nullptr, 0, y_up, SY2, D2c);
    // conv3 (C): conv3_w x y_up_tok -> d_out[192:384), fp32, BN+ReLU
    mfma_gemm<E_BNRELU_F32, false, true><<<dim3(36, 3, 2), blk, 0, stream>>>(
        conv3wb, 0, D2c, y_up, SY2, D2c, D2c,
        conv3_b, bn3_g, bn3_b, nullptr, 0,
        (float*)d_out + (long)Dc * NYc, SY2, NYc);
    // Q (T): y_c1_tok x wq -> Q_tok
    mfma_gemm<E_BIAS, false, false><<<dim3(6, 36, 2), blk, 0, stream>>>(
        y_c1, SY2, D2c, wqb, 0, D2c, D2c,
        wq_b, nullptr, nullptr, nullptr, 0, Qtok, SY2, D2c);
    // K (T): y_c1_tok x wk -> K_tok
    mfma_gemm<E_BIAS, false, false><<<dim3(6, 36, 2), blk, 0, stream>>>(
        y_c1, SY2, D2c, wkb, 0, D2c, D2c,
        wk_b, nullptr, nullptr, nullptr, 0, Ktok, SY2, D2c);
    // V (C): wv x s_c2_tok -> V_ch (channel-major)
    mfma_gemm<E_BIAS, false, true><<<dim3(36, 3, 2), blk, 0, stream>>>(
        wvb, 0, Dc, s_c2, SY1, Dc, Dc,
        wv_b, nullptr, nullptr, nullptr, 0, Vch, SY1, NYc);
    // attention
    attn_kernel<<<dim3(36, 16), blk, 0, stream>>>(Qtok, Ktok, Vch, Ztok);
    // sig gate (C): sig_w x Z_tok -> sigmoid(bn(.)) * s_pe_ch -> d_out[0:192), fp32
    mfma_gemm<E_SIG_F32, false, true><<<dim3(36, 3, 2), blk, 0, stream>>>(
        sigwb, 0, Dc, Ztok, SY1, Dc, Dc,
        sig_b, bnsig_g, bnsig_b, s_ch, SY1,
        (float*)d_out, SY2, NYc);
}

// Round 3
// 184.737 us; speedup vs baseline: 6.3213x; 1.2051x over previous
//
#include <hip/hip_runtime.h>
#include <hip/hip_bf16.h>

#define Dc   192
#define D2c  384
#define NYc  2304   // 48*48

// 1/sqrt(192) * log2(e): folded into wq weights+bias so QK^T scores are in
// log2 domain and softmax uses raw v_exp_f32 (= 2^x).
#define QSCALE 0.1041175462f

typedef __attribute__((ext_vector_type(8))) short short8;
typedef __attribute__((ext_vector_type(4))) float f32x4;

__device__ __forceinline__ unsigned short f2bf(float f) {
    unsigned int u = __float_as_uint(f);
    u += 0x7FFFu + ((u >> 16) & 1u);   // RNE
    return (unsigned short)(u >> 16);
}
__device__ __forceinline__ float fexp2(float x) {
    float r; asm("v_exp_f32 %0, %1" : "=v"(r) : "v"(x)); return r;
}
__device__ __forceinline__ unsigned cvtpk(float lo, float hi) {
    unsigned r; asm("v_cvt_pk_bf16_f32 %0, %1, %2" : "=v"(r) : "v"(lo), "v"(hi));
    return r;
}

// ---------------------------------------------------------------------------
__device__ __forceinline__ float pe_val(int c, int n, int C) {
    int x = n % 48, y = n / 48;
    int dh = C >> 1;
    float pos; int i;
    if (c < dh) { i = c >> 1;        pos = (float)x; }
    else        { i = (c - dh) >> 1; pos = (float)y; }
    float divv = expf((float)(2 * i) * (-9.210340371976184f / (float)dh));
    float ang = pos * divv;
    return (c & 1) ? cosf(ang) : sinf(ang);
}

__global__ __launch_bounds__(256)
void pe_y_kernel(const float* __restrict__ y, unsigned short* __restrict__ ytok) {
    int idx = blockIdx.x * 256 + threadIdx.x;
    int n = idx % NYc; int c = (idx / NYc) % D2c; int b = idx / (NYc * D2c);
    float v = y[idx] + pe_val(c, n, D2c);
    ytok[(long)b * NYc * D2c + (long)n * D2c + c] = f2bf(v);
}

__global__ __launch_bounds__(256)
void pe_s_kernel(const float* __restrict__ s, unsigned short* __restrict__ stok,
                 float* __restrict__ sch) {
    int idx = blockIdx.x * 256 + threadIdx.x;
    int n = idx % NYc; int c = (idx / NYc) % Dc; int b = idx / (NYc * Dc);
    float v = s[idx] + pe_val(c, n, Dc);
    sch[idx] = v;
    stok[(long)b * NYc * Dc + (long)n * Dc + c] = f2bf(v);
}

// seven 1x1 weight matrices -> bf16 (wq region pre-scaled), plus concat bias
__global__ __launch_bounds__(256)
void cvt_w_kernel(const float* __restrict__ w0, const float* __restrict__ w1,
                  const float* __restrict__ w2, const float* __restrict__ w3,
                  const float* __restrict__ w4, const float* __restrict__ w5,
                  const float* __restrict__ w6, unsigned short* __restrict__ dst,
                  const float* __restrict__ wq_b, const float* __restrict__ wk_b,
                  float* __restrict__ qkb) {
    int idx = blockIdx.x * 256 + threadIdx.x;   // total 626688
    if (idx < 768)
        qkb[idx] = (idx < 384) ? wq_b[idx] * QSCALE : wk_b[idx - 384];
    const float* src; int off; float scl = 1.0f;
    if      (idx < 147456) { src = w0; off = idx; }
    else if (idx < 294912) { src = w1; off = idx - 147456; scl = QSCALE; }
    else if (idx < 442368) { src = w2; off = idx - 294912; }
    else if (idx < 479232) { src = w3; off = idx - 442368; }
    else if (idx < 516096) { src = w4; off = idx - 479232; }
    else if (idx < 552960) { src = w5; off = idx - 516096; }
    else                   { src = w6; off = idx - 552960; }
    dst[idx] = f2bf(src[off] * scl);
}

// up_w (O,C,3,3) fp32 -> up_wt bf16 [O][tap*384 + c]
__global__ __launch_bounds__(256)
void cvt_up_kernel(const float* __restrict__ w, unsigned short* __restrict__ wt) {
    int idx = blockIdx.x * 256 + threadIdx.x;   // total 384*3456
    int o = idx / 3456; int r = idx % 3456;
    int tap = r / 384;  int c = r % 384;
    wt[idx] = f2bf(w[((long)o * 384 + c) * 9 + tap]);
}

// ---------------------------------------------------------------------------
// bf16 MFMA GEMM, 64x64 tile, BK=64, 4 waves (each 32x32 = 2x2 of 16x16x32).
// D[m][n] = sum_k A'[m][k] * B'[n][k] (+ epilogue); A',B' row-major [free][k].
// ---------------------------------------------------------------------------
enum { E_BIAS = 0, E_BNRELU = 1, E_BNRELU_F32 = 2, E_SIG_F32 = 3 };

template<int EPI, bool IM2COL, bool CH_M>
__global__ __launch_bounds__(256)
void mfma_gemm(const unsigned short* __restrict__ Ar, long aBatch, int aPitch,
               const unsigned short* __restrict__ Br, long bBatch, int bPitch,
               int K,
               const float* __restrict__ bias, const float* __restrict__ bng,
               const float* __restrict__ bnb,
               const float* __restrict__ smul, long smulBatch,
               void* __restrict__ outv, long oBatch, int oPitch)
{
    int b = blockIdx.z;
    const unsigned short* A = Ar + (long)b * aBatch;
    const unsigned short* B = Br + (long)b * bBatch;
    int n0 = blockIdx.x * 64, m0 = blockIdx.y * 64;

    __shared__ __align__(16) unsigned short As[64][72];
    __shared__ __align__(16) unsigned short Bs[64][72];

    int t = threadIdx.x;
    int lane = t & 63, w = t >> 6;
    int lr = lane & 15, lg = lane >> 4;
    int wm = (w >> 1) * 32, wn = (w & 1) * 32;

    f32x4 zero = {0.f, 0.f, 0.f, 0.f};
    f32x4 acc[2][2] = {{zero, zero}, {zero, zero}};

    for (int k0 = 0; k0 < K; k0 += 64) {
        #pragma unroll
        for (int i = 0; i < 2; ++i) {
            int idx = t + i * 256;
            int row = idx >> 3, sl = idx & 7;
            uint4 av;
            if (!IM2COL) {
                av = *(const uint4*)(A + (long)(m0 + row) * aPitch + k0 + sl * 8);
            } else {
                int gk = k0 + sl * 8;
                int tap = gk / 384;
                int rem = gk - tap * 384;
                int tok = m0 + row;
                int py = tok / 48 + tap / 3 - 1;
                int px = tok % 48 + tap % 3 - 1;
                av = (py >= 0 && py < 48 && px >= 0 && px < 48)
                        ? *(const uint4*)(A + (long)(py * 48 + px) * aPitch + rem)
                        : make_uint4(0, 0, 0, 0);
            }
            uint4 bv = *(const uint4*)(B + (long)(n0 + row) * bPitch + k0 + sl * 8);
            *(uint4*)&As[row][sl * 8] = av;
            *(uint4*)&Bs[row][sl * 8] = bv;
        }
        __syncthreads();
        #pragma unroll
        for (int kk = 0; kk < 2; ++kk) {
            short8 a0 = *(const short8*)&As[wm + lr][kk * 32 + lg * 8];
            short8 a1 = *(const short8*)&As[wm + 16 + lr][kk * 32 + lg * 8];
            short8 b0 = *(const short8*)&Bs[wn + lr][kk * 32 + lg * 8];
            short8 b1 = *(const short8*)&Bs[wn + 16 + lr][kk * 32 + lg * 8];
            acc[0][0] = __builtin_amdgcn_mfma_f32_16x16x32_bf16(a0, b0, acc[0][0], 0, 0, 0);
            acc[0][1] = __builtin_amdgcn_mfma_f32_16x16x32_bf16(a0, b1, acc[0][1], 0, 0, 0);
            acc[1][0] = __builtin_amdgcn_mfma_f32_16x16x32_bf16(a1, b0, acc[1][0], 0, 0, 0);
            acc[1][1] = __builtin_amdgcn_mfma_f32_16x16x32_bf16(a1, b1, acc[1][1], 0, 0, 0);
        }
        __syncthreads();
    }

    float* outF = (float*)outv;
    unsigned short* outH = (unsigned short*)outv;
    long ob = (long)b * oBatch;
    #pragma unroll
    for (int i = 0; i < 2; ++i)
    #pragma unroll
    for (int j = 0; j < 2; ++j)
    #pragma unroll
    for (int r = 0; r < 4; ++r) {
        int gm = m0 + wm + i * 16 + lg * 4 + r;
        int gn = n0 + wn + j * 16 + lr;
        int ch = CH_M ? gm : gn;
        float v = acc[i][j][r] + bias[ch];
        if (EPI == E_BNRELU || EPI == E_BNRELU_F32)
            v = fmaxf(fmaf(v, bng[ch], bnb[ch]), 0.f);
        if (EPI == E_SIG_F32) {
            v = fmaf(v, bng[ch], bnb[ch]);
            v = 1.f / (1.f + __expf(-v));
            v *= smul[(long)b * smulBatch + (long)gm * NYc + gn];
        }
        long o = ob + (long)gm * oPitch + gn;
        if (EPI == E_BNRELU_F32 || EPI == E_SIG_F32) outF[o] = v;
        else                                         outH[o] = f2bf(v);
    }
}

// ---------------------------------------------------------------------------
// Fused MFMA flash attention, swapped-QK^T + in-register softmax row.
// QK: bf16 [b][2304][768] (Q at col h*48, K at col 384+h*48; Q pre-scaled by
// QSCALE so scores are log2-domain). Vc: bf16 [b][192][2304]. Z: [b][2304][192].
// 512 threads = 8 waves = 4 q-teams (16 q each) x 2 key-splits. KVBLK=128.
// ---------------------------------------------------------------------------
__global__ __launch_bounds__(512)
void attn_kernel(const unsigned short* __restrict__ QK,
                 const unsigned short* __restrict__ Vc,
                 unsigned short* __restrict__ Zt)
{
    int qb = blockIdx.x;                 // 0..35
    int bh = blockIdx.y;                 // 0..15
    int b = bh >> 3, h = bh & 7;
    const unsigned short* Qg = QK + (long)b * NYc * 768 + h * 48;
    const unsigned short* Kg = Qg + 384;
    const unsigned short* Vg = Vc + ((long)b * Dc + h * 24) * NYc;
    unsigned short*       Z  = Zt + (long)b * NYc * Dc + h * 24;

    __shared__ __align__(16) unsigned short Ks_[128][72];
    __shared__ __align__(16) unsigned short Vs_[32][136];
    __shared__ __align__(16) unsigned int   Ps_[8][16][36];

    int t = threadIdx.x, lane = t & 63, w = t >> 6;
    int lr = lane & 15, lg = lane >> 4;
    int tm = w >> 1, hf = w & 1;
    int q0 = qb * 64;

    // Q fragments direct from global (cols >=48 are zero padding)
    short8 z8 = {0, 0, 0, 0, 0, 0, 0, 0};
    const unsigned short* qrow = Qg + (long)(q0 + tm * 16 + lr) * 768;
    short8 bq0 = *(const short8*)(qrow + lg * 8);
    short8 bq1 = (lg < 2) ? *(const short8*)(qrow + 32 + lg * 8) : z8;

    float m_run = -1e30f, l_run = 0.f;
    f32x4 O0 = {0.f, 0.f, 0.f, 0.f}, O1 = {0.f, 0.f, 0.f, 0.f};

    for (int kt = 0; kt < 18; ++kt) {
        long k0 = kt * 128;
        #pragma unroll
        for (int i = 0; i < 2; ++i) {           // K tile: 128 rows x 8 slots
            int idx = t + i * 512;
            int row = idx >> 3, sl = idx & 7;
            uint4 v = make_uint4(0, 0, 0, 0);
            if (sl < 6) v = *(const uint4*)(Kg + (k0 + row) * 768 + sl * 8);
            *(uint4*)&Ks_[row][sl * 8] = v;
        }
        if (t < 384) {                          // V tile: 24 rows x 16 slots
            int row = t >> 4, sl = t & 15;
            *(uint4*)&Vs_[row][sl * 8] =
                *(const uint4*)(Vg + (long)row * NYc + k0 + sl * 8);
        }
        __syncthreads();

        // S^T = K Q^T : lane holds S[k = ks*16+lg*4+r][q = lr]
        f32x4 sS[4];
        #pragma unroll
        for (int ks = 0; ks < 4; ++ks) {
            short8 ak0 = *(const short8*)&Ks_[hf * 64 + ks * 16 + lr][lg * 8];
            short8 ak1 = *(const short8*)&Ks_[hf * 64 + ks * 16 + lr][32 + lg * 8];
            f32x4 c = {0.f, 0.f, 0.f, 0.f};
            c = __builtin_amdgcn_mfma_f32_16x16x32_bf16(ak0, bq0, c, 0, 0, 0);
            c = __builtin_amdgcn_mfma_f32_16x16x32_bf16(ak1, bq1, c, 0, 0, 0);
            sS[ks] = c;
        }

        float tmax = -1e30f;
        #pragma unroll
        for (int ks = 0; ks < 4; ++ks)
            #pragma unroll
            for (int r = 0; r < 4; ++r) tmax = fmaxf(tmax, sS[ks][r]);
        tmax = fmaxf(tmax, __shfl_xor(tmax, 16));
        tmax = fmaxf(tmax, __shfl_xor(tmax, 32));

        if (__any(tmax > m_run + 10.f)) {       // rescale path (rare after warmup)
            float mn = fmaxf(m_run, tmax);
            float al = fexp2(m_run - mn);
            m_run = mn;
            l_run *= al;
            #pragma unroll
            for (int rr = 0; rr < 4; ++rr) {
                float arr = __shfl(al, (lane & 48) | (lg * 4 + rr));
                O0[rr] *= arr; O1[rr] *= arr;
            }
        }

        float psum = 0.f;
        #pragma unroll
        for (int ks = 0; ks < 4; ++ks) {
            float p0 = fexp2(sS[ks][0] - m_run);
            float p1 = fexp2(sS[ks][1] - m_run);
            float p2 = fexp2(sS[ks][2] - m_run);
            float p3 = fexp2(sS[ks][3] - m_run);
            psum += (p0 + p1) + (p2 + p3);
            Ps_[w][lr][8 * ks + 2 * lg]     = cvtpk(p0, p1);
            Ps_[w][lr][8 * ks + 2 * lg + 1] = cvtpk(p2, p3);
        }
        psum += __shfl_xor(psum, 16);
        psum += __shfl_xor(psum, 32);
        l_run += psum;

        // O += P V  (A = P rows q=lr, k-contig; B = V rows dv, k-contig)
        short8 ap0 = *(const short8*)&Ps_[w][lr][4 * lg];
        short8 ap1 = *(const short8*)&Ps_[w][lr][16 + 4 * lg];
        short8 bv00 = *(const short8*)&Vs_[lr][hf * 64 + lg * 8];
        short8 bv01 = *(const short8*)&Vs_[lr][hf * 64 + 32 + lg * 8];
        short8 bv10 = *(const short8*)&Vs_[16 + lr][hf * 64 + lg * 8];
        short8 bv11 = *(const short8*)&Vs_[16 + lr][hf * 64 + 32 + lg * 8];
        O0 = __builtin_amdgcn_mfma_f32_16x16x32_bf16(ap0, bv00, O0, 0, 0, 0);
        O0 = __builtin_amdgcn_mfma_f32_16x16x32_bf16(ap1, bv01, O0, 0, 0, 0);
        O1 = __builtin_amdgcn_mfma_f32_16x16x32_bf16(ap0, bv10, O1, 0, 0, 0);
        O1 = __builtin_amdgcn_mfma_f32_16x16x32_bf16(ap1, bv11, O1, 0, 0, 0);
        __syncthreads();
    }

    // combine the two key-split waves of each team (reuse Ps_ as float scratch)
    float* Cf = (float*)&Ps_[0][0][0];
    float* T = Cf + tm * 576;
    if (hf == 1) {
        #pragma unroll
        for (int j = 0; j < 4; ++j) {
            T[lane * 8 + j]     = O0[j];
            T[lane * 8 + 4 + j] = O1[j];
        }
        if (lane < 16) { T[512 + lane] = m_run; T[528 + lane] = l_run; }
    }
    __syncthreads();
    if (hf == 0) {
        float mB = T[512 + lr], lB = T[528 + lr];
        float mS = fmaxf(m_run, mB);
        float aA = fexp2(m_run - mS), aB = fexp2(mB - mS);
        float invl = 1.f / (l_run * aA + lB * aB);
        float fA = aA * invl, fB = aB * invl;
        #pragma unroll
        for (int rr = 0; rr < 4; ++rr) {
            int src = (lane & 48) | (lg * 4 + rr);
            float gA = __shfl(fA, src), gB = __shfl(fB, src);
            int n = q0 + tm * 16 + lg * 4 + rr;
            unsigned short* zr = Z + (long)n * Dc;
            float z0 = O0[rr] * gA + T[lane * 8 + rr] * gB;
            zr[lr] = f2bf(z0);
            if (lr < 8) {
                float z1 = O1[rr] * gA + T[lane * 8 + 4 + rr] * gB;
                zr[16 + lr] = f2bf(z1);
            }
        }
    }
}

// ---------------------------------------------------------------------------
extern "C" void kernel_launch(void* const* d_in, const int* in_sizes, int n_in,
                              void* d_out, int out_size, void* d_ws, size_t ws_size,
                              hipStream_t stream) {
    const float* y       = (const float*)d_in[0];
    const float* s       = (const float*)d_in[1];
    const float* wq_w    = (const float*)d_in[2];
    const float* wq_b    = (const float*)d_in[3];
    const float* wk_w    = (const float*)d_in[4];
    const float* wk_b    = (const float*)d_in[5];
    const float* wv_w    = (const float*)d_in[6];
    const float* wv_b    = (const float*)d_in[7];
    const float* conv1_w = (const float*)d_in[8];
    const float* conv1_b = (const float*)d_in[9];
    const float* bn1_g   = (const float*)d_in[10];
    const float* bn1_b   = (const float*)d_in[11];
    const float* conv2_w = (const float*)d_in[12];
    const float* conv2_b = (const float*)d_in[13];
    const float* bn2_g   = (const float*)d_in[14];
    const float* bn2_b   = (const float*)d_in[15];
    const float* up_w    = (const float*)d_in[16];
    const float* up_b    = (const float*)d_in[17];
    const float* conv3_w = (const float*)d_in[18];
    const float* conv3_b = (const float*)d_in[19];
    const float* bn3_g   = (const float*)d_in[20];
    const float* bn3_b   = (const float*)d_in[21];
    const float* sig_w   = (const float*)d_in[22];
    const float* sig_b   = (const float*)d_in[23];
    const float* bnsig_g = (const float*)d_in[24];
    const float* bnsig_b = (const float*)d_in[25];

    unsigned short* wsp  = (unsigned short*)d_ws;
    unsigned short* wcvt  = wsp;                     // 626688
    unsigned short* upwt  = wcvt + 626688;           // 1327104
    unsigned short* y_pe  = upwt + 1327104;          // 1769472
    unsigned short* s_pe  = y_pe + 1769472;          //  884736
    unsigned short* y_c1  = s_pe + 884736;           // 1769472
    unsigned short* s_c2  = y_c1 + 1769472;          //  884736
    unsigned short* y_up  = s_c2 + 884736;           // 1769472
    unsigned short* QKtok = y_up + 1769472;          // 3538944  [b][n][768]
    unsigned short* Vch   = QKtok + 3538944;         //  884736
    unsigned short* Ztok  = Vch + 884736;            //  884736
    float*          s_ch  = (float*)(Ztok + 884736); //  884736 fp32
    float*          qkb   = s_ch + 884736;           //  768 fp32

    const unsigned short* conv1wb = wcvt;
    const unsigned short* wqkb    = wcvt + 147456;   // wq||wk, 768 x 384
    const unsigned short* conv2wb = wcvt + 442368;
    const unsigned short* wvb     = wcvt + 479232;
    const unsigned short* sigwb   = wcvt + 516096;
    const unsigned short* conv3wb = wcvt + 552960;

    const long SY2 = (long)D2c * NYc;   // 884736
    const long SY1 = (long)Dc * NYc;    // 442368

    pe_y_kernel<<<(2 * D2c * NYc) / 256, 256, 0, stream>>>(y, y_pe);
    pe_s_kernel<<<(2 * Dc * NYc) / 256, 256, 0, stream>>>(s, s_pe, s_ch);
    cvt_w_kernel<<<626688 / 256, 256, 0, stream>>>(conv1_w, wq_w, wk_w, conv2_w,
                                                   wv_w, sig_w, conv3_w, wcvt,
                                                   wq_b, wk_b, qkb);
    cvt_up_kernel<<<1327104 / 256, 256, 0, stream>>>(up_w, upwt);

    dim3 blk(256);
    // conv1: y_pe_tok x conv1_w -> y_c1_tok, BN+ReLU
    mfma_gemm<E_BNRELU, false, false><<<dim3(6, 36, 2), blk, 0, stream>>>(
        y_pe, SY2, D2c, conv1wb, 0, D2c, D2c,
        conv1_b, bn1_g, bn1_b, nullptr, 0, y_c1, SY2, D2c);
    // conv2: s_pe_tok x conv2_w -> s_c2_tok, BN+ReLU
    mfma_gemm<E_BNRELU, false, false><<<dim3(3, 36, 2), blk, 0, stream>>>(
        s_pe, SY1, Dc, conv2wb, 0, Dc, Dc,
        conv2_b, bn2_g, bn2_b, nullptr, 0, s_c2, SY1, Dc);
    // up: im2col 3x3, y_pe_tok x up_wt -> y_up_tok, bias
    mfma_gemm<E_BIAS, true, false><<<dim3(6, 36, 2), blk, 0, stream>>>(
        y_pe, SY2, D2c, upwt, 0, 9 * D2c, 9 * D2c,
        up_b, nullptr, nullptr, nullptr, 0, y_up, SY2, D2c);
    // conv3: conv3_w x y_up_tok -> d_out[192:384), fp32 BN+ReLU
    mfma_gemm<E_BNRELU_F32, false, true><<<dim3(36, 3, 2), blk, 0, stream>>>(
        conv3wb, 0, D2c, y_up, SY2, D2c, D2c,
        conv3_b, bn3_g, bn3_b, nullptr, 0,
        (float*)d_out + (long)Dc * NYc, SY2, NYc);
    // fused Q+K projection: y_c1_tok x (wq||wk) -> QKtok [n][768]
    mfma_gemm<E_BIAS, false, false><<<dim3(12, 36, 2), blk, 0, stream>>>(
        y_c1, SY2, D2c, wqkb, 0, D2c, D2c,
        qkb, nullptr, nullptr, nullptr, 0, QKtok, (long)NYc * 768, 768);
    // V: wv x s_c2_tok -> V_ch
    mfma_gemm<E_BIAS, false, true><<<dim3(36, 3, 2), blk, 0, stream>>>(
        wvb, 0, Dc, s_c2, SY1, Dc, Dc,
        wv_b, nullptr, nullptr, nullptr, 0, Vch, SY1, NYc);
    // attention
    attn_kernel<<<dim3(36, 16), dim3(512), 0, stream>>>(QKtok, Vch, Ztok);
    // sigmoid gate: sig_w x Z_tok -> sigmoid(bn(.)) * s_pe -> d_out[0:192), fp32
    mfma_gemm<E_SIG_F32, false, true><<<dim3(36, 3, 2), blk, 0, stream>>>(
        sigwb, 0, Dc, Ztok, SY1, Dc, Dc,
        sig_b, bnsig_g, bnsig_b, s_ch, SY1,
        (float*)d_out, SY2, NYc);
}